// Round 1
// baseline (81.423 us; speedup 1.0000x reference)
//
#include <hip/hip_runtime.h>
#include <math.h>

// TropConv2D: out[b,ho,wo,f] = max_k(patch + w) - min_k(patch + w) + bias
// B=8, H=W=32, C=32, KH=KW=3, F=64, Ho=Wo=30, K=288. 7200 output pixels.
//
// R3 structure: 512-thread blocks (8 waves), each wave owns PIX=2 pixels,
// lane = filter. w (288x64 = 72 KiB) is staged in TWO phases instead of
// nine per-tap rounds: phase A = taps 0..4 (40 KiB LDS), phase B = taps
// 5..8 prefetched into registers before the first barrier and written to
// LDS after compute-A. 3 barriers/block instead of 9, and each compute
// phase is a single long unrolled stream the scheduler can pipeline.
// min/max chains are reassociated for v_max3/v_min3 fusion.
// 450 blocks => ~14 waves/CU; LDS 40 KiB/block never limits occupancy
// at <=2 blocks/CU.

#define TPB 512  // 8 waves
#define PIX 2
#define NTA 5    // taps in phase A (LDS resident: 5*2048 floats = 40 KiB)
#define NTB 4    // taps in phase B

__device__ __forceinline__ float fmax3(float a, float b, float c) {
    return fmaxf(fmaxf(a, b), c);
}
__device__ __forceinline__ float fmin3(float a, float b, float c) {
    return fminf(fminf(a, b), c);
}

template <int T0, int NT>
__device__ __forceinline__ void compute_taps(
    const float* __restrict__ wl, const float* const* xp, int lane,
    float* amax, float* amin)
{
#pragma unroll
    for (int t = 0; t < NT; ++t) {
        const int tap = T0 + t;
        const int dy = tap / 3;
        const int dx = tap % 3;
        const int xoff = (dy * 32 + dx) * 32;
#pragma unroll
        for (int c = 0; c < 32; c += 4) {
            const float w0 = wl[t * 2048 + (c + 0) * 64 + lane];
            const float w1 = wl[t * 2048 + (c + 1) * 64 + lane];
            const float w2 = wl[t * 2048 + (c + 2) * 64 + lane];
            const float w3 = wl[t * 2048 + (c + 3) * 64 + lane];
#pragma unroll
            for (int p = 0; p < PIX; ++p) {
                const float4 xv = *(const float4*)(xp[p] + xoff + c);  // wave-uniform
                const float s0 = xv.x + w0;
                const float s1 = xv.y + w1;
                const float s2 = xv.z + w2;
                const float s3 = xv.w + w3;
                // 2x v_max3 / 2x v_min3 after fusion
                amax[p] = fmax3(amax[p], fmax3(s0, s1, s2), s3);
                amin[p] = fmin3(amin[p], fmin3(s0, s1, s2), s3);
            }
        }
    }
}

__global__ __launch_bounds__(TPB) void trop_kernel(
    const float* __restrict__ x,     // (8,32,32,32)
    const float* __restrict__ w,     // (288,64) = 9 taps * (32,64)
    const float* __restrict__ bias,  // (64,)
    float* __restrict__ out)         // (8,30,30,64) = (7200,64)
{
    __shared__ float wlds[NTA * 2048];  // 40 KiB

    const int tid  = threadIdx.x;
    const int lane = tid & 63;
    const int wv   = tid >> 6;

    const int pix0 = blockIdx.x * (8 * PIX) + wv * PIX;  // 0..7198

    const float* xp[PIX];
#pragma unroll
    for (int p = 0; p < PIX; ++p) {
        const int pid = pix0 + p;
        const int wo = pid % 30;
        const int t  = pid / 30;
        const int ho = t % 30;
        const int b  = t / 30;
        xp[p] = x + (((b * 32 + ho) * 32) + wo) * 32;
    }

    // Stage phase A: taps 0..4 = 2560 float4 across 512 threads (5 each).
    {
        const float4* src = (const float4*)w;
        float4* dst = (float4*)wlds;
#pragma unroll
        for (int i = 0; i < 5; ++i) dst[tid + i * 512] = src[tid + i * 512];
    }
    // Prefetch phase B (taps 5..8 = 2048 float4, 4 each) into registers;
    // these loads stay in flight across all of compute-A.
    float4 rB[4];
    {
        const float4* src = (const float4*)(w + NTA * 2048);
#pragma unroll
        for (int i = 0; i < 4; ++i) rB[i] = src[tid + i * 512];
    }
    __syncthreads();

    float amax[PIX], amin[PIX];
#pragma unroll
    for (int p = 0; p < PIX; ++p) { amax[p] = -INFINITY; amin[p] = INFINITY; }

    compute_taps<0, NTA>(wlds, xp, lane, amax, amin);

    __syncthreads();  // everyone done reading phase-A slices
    {
        float4* dst = (float4*)wlds;
#pragma unroll
        for (int i = 0; i < 4; ++i) dst[tid + i * 512] = rB[i];
    }
    __syncthreads();

    compute_taps<NTA, NTB>(wlds, xp, lane, amax, amin);

    const float bv = bias[lane];
#pragma unroll
    for (int p = 0; p < PIX; ++p)
        out[(pix0 + p) * 64 + lane] = amax[p] - amin[p] + bv;
}

extern "C" void kernel_launch(void* const* d_in, const int* in_sizes, int n_in,
                              void* d_out, int out_size, void* d_ws, size_t ws_size,
                              hipStream_t stream) {
    const float* x    = (const float*)d_in[0];
    const float* w    = (const float*)d_in[1];
    const float* bias = (const float*)d_in[2];
    float* out = (float*)d_out;

    // 7200 pixels / (8 waves * 2 pixels) = 450 blocks
    trop_kernel<<<dim3(450), dim3(TPB), 0, stream>>>(x, w, bias, out);
}

// Round 2
// 68.087 us; speedup vs baseline: 1.1959x; 1.1959x over previous
//
#include <hip/hip_runtime.h>
#include <math.h>

// TropConv2D: out[b,ho,wo,f] = max_k(patch + w) - min_k(patch + w) + bias
// B=8, H=W=32, C=32, KH=KW=3, F=64, Ho=Wo=30, K=288. 7200 output pixels.
//
// R4 structure: 512-thread blocks (8 waves), wave owns PIX=2 pixels,
// lane = filter.
//  * ALL of w (288x64 = 72 KiB) staged into dynamic LDS once -> ONE
//    barrier per block, no double-buffer, no prefetch registers.
//    72 KiB/WG -> 2 blocks/CU by LDS; 450 blocks all co-resident.
//  * x row segments are wave-uniform: pixel offset goes through
//    readfirstlane so the compiler can prove uniformity and emit
//    s_load (SGPR) instead of per-wave VMEM -> no VMEM latency chain
//    in the inner loop; adds are v_add_f32 v,s,v.
//  * w reads are lane-consecutive ds_read_b32 (bank-conflict-free,
//    2 lanes/bank aliasing is free).
//  * max/min reassociated for v_max3/v_min3.

#define TPB 512  // 8 waves
#define PIX 2

__device__ __forceinline__ float fmax3(float a, float b, float c) {
    return fmaxf(fmaxf(a, b), c);
}
__device__ __forceinline__ float fmin3(float a, float b, float c) {
    return fminf(fminf(a, b), c);
}

__global__ __launch_bounds__(TPB) void trop_kernel(
    const float* __restrict__ x,     // (8,32,32,32)
    const float* __restrict__ w,     // (288,64) = 9 taps * (32,64)
    const float* __restrict__ bias,  // (64,)
    float* __restrict__ out)         // (8,30,30,64) = (7200,64)
{
    extern __shared__ float wlds[];  // 18432 floats = 72 KiB

    const int tid  = threadIdx.x;
    const int lane = tid & 63;
    const int wv   = tid >> 6;

    const int pix0 = blockIdx.x * (8 * PIX) + wv * PIX;  // 0..7198

    // Stage ALL of w: 4608 float4 across 512 threads = 9 each.
    {
        const float4* src = (const float4*)w;
        float4* dst = (float4*)wlds;
#pragma unroll
        for (int i = 0; i < 9; ++i) dst[tid + i * 512] = src[tid + i * 512];
    }

    // Wave-uniform x base offsets (in floats), hoisted to SGPR.
    int xoffp[PIX];
#pragma unroll
    for (int p = 0; p < PIX; ++p) {
        const int pid = pix0 + p;
        const int wo = pid % 30;
        const int t  = pid / 30;
        const int ho = t % 30;
        const int b  = t / 30;
        xoffp[p] = __builtin_amdgcn_readfirstlane((((b * 32 + ho) * 32) + wo) * 32);
    }

    float amax[PIX], amin[PIX];
#pragma unroll
    for (int p = 0; p < PIX; ++p) { amax[p] = -INFINITY; amin[p] = INFINITY; }

    __syncthreads();  // the only barrier

#pragma unroll
    for (int tap = 0; tap < 9; ++tap) {
        const int dy = tap / 3;
        const int dx = tap % 3;
        const int xoff = (dy * 32 + dx) * 32;
        const float* wl = wlds + tap * 2048;
#pragma unroll
        for (int c = 0; c < 32; c += 4) {
            const float w0 = wl[(c + 0) * 64 + lane];
            const float w1 = wl[(c + 1) * 64 + lane];
            const float w2 = wl[(c + 2) * 64 + lane];
            const float w3 = wl[(c + 3) * 64 + lane];
#pragma unroll
            for (int p = 0; p < PIX; ++p) {
                const float* xb = x + xoffp[p] + xoff;  // scalar (SGPR) address
                const float s0 = xb[c + 0] + w0;
                const float s1 = xb[c + 1] + w1;
                const float s2 = xb[c + 2] + w2;
                const float s3 = xb[c + 3] + w3;
                amax[p] = fmax3(amax[p], fmax3(s0, s1, s2), s3);
                amin[p] = fmin3(amin[p], fmin3(s0, s1, s2), s3);
            }
        }
    }

    const float bv = bias[lane];
#pragma unroll
    for (int p = 0; p < PIX; ++p)
        out[(pix0 + p) * 64 + lane] = amax[p] - amin[p] + bv;
}

extern "C" void kernel_launch(void* const* d_in, const int* in_sizes, int n_in,
                              void* d_out, int out_size, void* d_ws, size_t ws_size,
                              hipStream_t stream) {
    const float* x    = (const float*)d_in[0];
    const float* w    = (const float*)d_in[1];
    const float* bias = (const float*)d_in[2];
    float* out = (float*)d_out;

    // Allow 72 KiB dynamic LDS (gfx950 has 160 KiB/CU).
    static int attr_done = 0;
    if (!attr_done) {
        (void)hipFuncSetAttribute((const void*)trop_kernel,
                                  hipFuncAttributeMaxDynamicSharedMemorySize,
                                  73728);
        attr_done = 1;
    }

    // 7200 pixels / (8 waves * 2 pixels) = 450 blocks
    trop_kernel<<<dim3(450), dim3(TPB), 73728, stream>>>(x, w, bias, out);
}